// Round 5
// baseline (232.126 us; speedup 1.0000x reference)
//
#include <hip/hip_runtime.h>
#include <hip/hip_bf16.h>
#include <math.h>

// Problem constants
#define NPIX   25600      // H*W = 160*160
#define CDIM   256
#define SSEL   1024       // MAX_SAMPLES
#define BATCH  4
#define NCHUNK 25         // NPIX / 1024
#define INV_T  10.0f      // 1/TEMP
#define RATIO  1.4285714285714286f  // TEMP/BASE_TEMP
#define THR    0.7f

typedef __attribute__((ext_vector_type(8))) short bf16x8;
typedef __attribute__((ext_vector_type(4))) float f32x4;

// ---------------------------------------------------------------------------
// Kernel 0: pack weights + zero accumulators + per-chunk valid counts.
// ---------------------------------------------------------------------------
__global__ __launch_bounds__(256) void pack_weights(
    const float* __restrict__ w1, const float* __restrict__ w2,
    const float* __restrict__ wa1, const int* __restrict__ labels,
    float* __restrict__ w1p, float* __restrict__ w2p, float* __restrict__ wa1p,
    float* __restrict__ denom, float* __restrict__ Prow, float* __restrict__ Ssum,
    int* __restrict__ counts) {
  int t = threadIdx.x;
  int e = blockIdx.x * 256 + t;
  if (e < 65536) {
    int kk = e & 3;
    int c  = (e >> 2) & 255;
    int k4 = e >> 10;
    int src = c * 256 + k4 * 4 + kk;
    w1p[e] = w1[src];
    w2p[e] = w2[src];
  }
  if (e < 16384) {
    int kk = e & 3;
    int c  = (e >> 2) & 63;
    int k4 = e >> 8;
    wa1p[e] = wa1[c * 256 + k4 * 4 + kk];
  }
  if (e < BATCH * SSEL) { denom[e] = 0.f; Prow[e] = 0.f; }
  if (e < BATCH) Ssum[e] = 0.f;

  if (blockIdx.x < BATCH * NCHUNK) {
    int b = blockIdx.x / NCHUNK, ch = blockIdx.x % NCHUNK;
    const int* lab = labels + b * NPIX + ch * 1024;
    int local = 0;
#pragma unroll
    for (int q = 0; q < 4; ++q) local += (lab[q * 256 + t] == 1);
    for (int off = 32; off > 0; off >>= 1) local += __shfl_xor(local, off, 64);
    __shared__ int ws[4];
    if ((t & 63) == 0) ws[t >> 6] = local;
    __syncthreads();
    if (t == 0) counts[blockIdx.x] = ws[0] + ws[1] + ws[2] + ws[3];
  }
}

// ---------------------------------------------------------------------------
// Kernel 1: stable scatter ("valid first" order, first 1024 slots).
// ---------------------------------------------------------------------------
__global__ __launch_bounds__(1024) void select_scatter(
    const int* __restrict__ labels, const int* __restrict__ sp,
    const int* __restrict__ counts,
    int* __restrict__ idx, int* __restrict__ selv, int* __restrict__ tsp) {
  int b = blockIdx.x / NCHUNK, ch = blockIdx.x % NCHUNK;
  int t = threadIdx.x;
  __shared__ int cs[NCHUNK];
  __shared__ int wave_tot[16];
  if (t < NCHUNK) cs[t] = counts[b * NCHUNK + t];
  __syncthreads();
  int Vtot = 0, vbase = 0;
#pragma unroll
  for (int c = 0; c < NCHUNK; ++c) {
    int v = cs[c];
    Vtot += v;
    if (c < ch) vbase += v;
  }
  int ibase = ch * 1024 - vbase;

  int i = ch * 1024 + t;
  int isv = (labels[b * NPIX + i] == 1) ? 1 : 0;
  int lane = t & 63, wid = t >> 6;
  unsigned long long mv = __ballot(isv);
  int pv = __popcll(mv & ((1ull << lane) - 1ull));
  if (lane == 0) wave_tot[wid] = __popcll(mv);
  __syncthreads();
  for (int w = 0; w < wid; ++w) pv += wave_tot[w];
  int gslot = isv ? (vbase + pv) : (Vtot + ibase + (t - pv));
  if (gslot < SSEL) {
    idx [b * SSEL + gslot] = i;
    selv[b * SSEL + gslot] = isv;
    tsp [b * SSEL + gslot] = sp[b * NPIX + i];
  }
}

// ---------------------------------------------------------------------------
// Kernel 2: MLP. Thread = 8 channels (stride 32) x 2 rows: per wave per k4
// only 2 LDS reads (2-addr alias, free) + 8 coalesced L1 weight loads + 64
// fmac -> VALU-bound (LDS 96 cyc/CU < VALU 128 cyc/SIMD per k4).
// Emits fn as split bf16 planes (fnh + fnl) for the MFMA sim GEMM.
// ---------------------------------------------------------------------------
#define RROWS 16
__global__ __launch_bounds__(256) void mlp_kernel(
    const float* __restrict__ feats,
    const float* __restrict__ w1p, const float* __restrict__ b1,
    const float* __restrict__ w2p, const float* __restrict__ b2,
    const float* __restrict__ wa1p, const float* __restrict__ ba1,
    const float* __restrict__ wa2, const float* __restrict__ ba2,
    const int* __restrict__ idx,
    unsigned short* __restrict__ fnh, unsigned short* __restrict__ fnl,
    float* __restrict__ tw) {
  int r0  = blockIdx.x * RROWS;   // global row (b*1024 + slot)
  int b   = r0 >> 10;
  int t   = threadIdx.x;

  __shared__ float xs[RROWS][256];
  __shared__ float hs[RROWS][256];
  __shared__ float apart[RROWS][64];
  __shared__ float nrm[RROWS];
  __shared__ int   ridx[RROWS];

  if (t < RROWS) ridx[t] = idx[r0 + t];
  __syncthreads();

  for (int e = t; e < RROWS * 256; e += 256) {
    int r = e & 15, c = e >> 4;
    xs[r][c] = feats[((long)b * CDIM + c) * NPIX + ridx[r]];
  }
  __syncthreads();

  const float4* xs4  = reinterpret_cast<const float4*>(&xs[0][0]);
  const float4* hs4  = reinterpret_cast<const float4*>(&hs[0][0]);
  const float4* w1p4 = reinterpret_cast<const float4*>(w1p);
  const float4* w2p4 = reinterpret_cast<const float4*>(w2p);
  const float4* wa1p4= reinterpret_cast<const float4*>(wa1p);

  // ---- attn layer 1: thread = 1 row (t>>4) x 4 ch ((t&15)+16j) ----
  {
    int ca = t & 15, r = t >> 4;
    float aacc[4] = {0.f, 0.f, 0.f, 0.f};
#pragma unroll 2
    for (int k4 = 0; k4 < 64; ++k4) {
      float4 xv = xs4[r * 64 + k4];
#pragma unroll
      for (int j = 0; j < 4; ++j) {
        float4 wv = wa1p4[k4 * 64 + ca + 16 * j];
        aacc[j] += xv.x * wv.x + xv.y * wv.y + xv.z * wv.z + xv.w * wv.w;
      }
    }
#pragma unroll
    for (int j = 0; j < 4; ++j) {
      int cc = ca + 16 * j;
      apart[r][cc] = fmaxf(aacc[j] + ba1[cc], 0.f) * wa2[cc];
    }
  }

  // ---- layer 1: h = relu(x @ w1.T + b1) ----
  int c  = t & 31;      // channels c + 32*j, j=0..7
  int p  = t >> 5;      // row pair (0..7): rows 2p, 2p+1
  int ra = 2 * p, rb = 2 * p + 1;
  float acc0[8], acc1[8];
#pragma unroll
  for (int j = 0; j < 8; ++j) { acc0[j] = 0.f; acc1[j] = 0.f; }
#pragma unroll 2
  for (int k4 = 0; k4 < 64; ++k4) {
    float4 xa = xs4[ra * 64 + k4];
    float4 xb = xs4[rb * 64 + k4];
#pragma unroll
    for (int j = 0; j < 8; ++j) {
      float4 wv = w1p4[k4 * 256 + c + 32 * j];
      acc0[j] += xa.x * wv.x + xa.y * wv.y + xa.z * wv.z + xa.w * wv.w;
      acc1[j] += xb.x * wv.x + xb.y * wv.y + xb.z * wv.z + xb.w * wv.w;
    }
  }
#pragma unroll
  for (int j = 0; j < 8; ++j) {
    int cc = c + 32 * j;
    float bb = b1[cc];
    hs[ra][cc] = fmaxf(acc0[j] + bb, 0.f);
    hs[rb][cc] = fmaxf(acc1[j] + bb, 0.f);
  }
  __syncthreads();

  // ---- layer 2: fnpre = h @ w2.T + b2 ----
#pragma unroll
  for (int j = 0; j < 8; ++j) { acc0[j] = 0.f; acc1[j] = 0.f; }
#pragma unroll 2
  for (int k4 = 0; k4 < 64; ++k4) {
    float4 xa = hs4[ra * 64 + k4];
    float4 xb = hs4[rb * 64 + k4];
#pragma unroll
    for (int j = 0; j < 8; ++j) {
      float4 wv = w2p4[k4 * 256 + c + 32 * j];
      acc0[j] += xa.x * wv.x + xa.y * wv.y + xa.z * wv.z + xa.w * wv.w;
      acc1[j] += xb.x * wv.x + xb.y * wv.y + xb.z * wv.z + xb.w * wv.w;
    }
  }
#pragma unroll
  for (int j = 0; j < 8; ++j) {
    int cc = c + 32 * j;
    float bb = b2[cc];
    acc0[j] += bb;
    acc1[j] += bb;
  }

  // ---- row norms: 32-lane reduce (lanes sharing a row pair), plain store ----
  {
    float v0 = 0.f, v1 = 0.f;
#pragma unroll
    for (int j = 0; j < 8; ++j) { v0 += acc0[j] * acc0[j]; v1 += acc1[j] * acc1[j]; }
    for (int off = 16; off > 0; off >>= 1) {
      v0 += __shfl_xor(v0, off, 64);
      v1 += __shfl_xor(v1, off, 64);
    }
    if ((t & 31) == 0) { nrm[ra] = v0; nrm[rb] = v1; }
  }
  __syncthreads();
  {
    float dena = fmaxf(sqrtf(nrm[ra]), 1e-12f);
    float denb = fmaxf(sqrtf(nrm[rb]), 1e-12f);
    long roa = (long)(r0 + ra) * CDIM;
    long rob = (long)(r0 + rb) * CDIM;
#pragma unroll
    for (int j = 0; j < 8; ++j) {
      int cc = c + 32 * j;
      float va = acc0[j] / dena;
      float vb = acc1[j] / denb;
      __hip_bfloat16 ha = __float2bfloat16(va);
      __hip_bfloat16 hb = __float2bfloat16(vb);
      __hip_bfloat16 la = __float2bfloat16(va - __bfloat162float(ha));
      __hip_bfloat16 lb = __float2bfloat16(vb - __bfloat162float(hb));
      fnh[roa + cc] = *reinterpret_cast<unsigned short*>(&ha);
      fnh[rob + cc] = *reinterpret_cast<unsigned short*>(&hb);
      fnl[roa + cc] = *reinterpret_cast<unsigned short*>(&la);
      fnl[rob + cc] = *reinterpret_cast<unsigned short*>(&lb);
    }
  }

  // ---- attn finalize ----
  if (t < RROWS) {
    float s = ba2[0];
    for (int c2 = 0; c2 < 64; ++c2) s += apart[t][c2];
    tw[r0 + t] = 1.f / (1.f + expf(-s));
  }
}

// ---------------------------------------------------------------------------
// Kernel 3: MFMA sim = fn @ fn.T (split-bf16: HH + HL + LH ~= fp32).
// Triangular tiles tj>=ti, 64x64 per block, 4 waves; wave w computes rows
// w*16..+15 x all 64 cols via 4 accumulators of mfma_f32_16x16x32_bf16.
// LDS row stride 72 ushorts -> frag reads 2-way (free).
// ---------------------------------------------------------------------------
__global__ __launch_bounds__(256) void sim_kernel(
    const unsigned short* __restrict__ fnh, const unsigned short* __restrict__ fnl,
    const float* __restrict__ tw,
    const int* __restrict__ selv, const int* __restrict__ tsp,
    float* __restrict__ denom, float* __restrict__ Prow, float* __restrict__ Ssum) {
  int b = blockIdx.y;
  int t = threadIdx.x;
  int lane = t & 63, w = t >> 6;
  int m = lane & 15, q = lane >> 4;

  // triangular tile mapping: blockIdx.x in [0,136) -> (ti,tj), tj>=ti
  int rem = blockIdx.x, ti = 0;
  while (rem >= (16 - ti)) { rem -= (16 - ti); ++ti; }
  int tj = ti + rem;
  bool diag = (ti == tj);
  int i0 = ti * 64, j0 = tj * 64;
  int base = b << 10;

  __shared__ __align__(16) unsigned short Ah[64 * 72], Al[64 * 72];
  __shared__ __align__(16) unsigned short Bhh[64 * 72], Bll[64 * 72];
  __shared__ float drl[64], Prl[64];
  __shared__ float dclw[4][64], Pclw[4][64];
  __shared__ float swv[4];

  const unsigned short* Bh = diag ? Ah : Bhh;
  const unsigned short* Bl = diag ? Al : Bll;

  f32x4 acc[4];
#pragma unroll
  for (int nt = 0; nt < 4; ++nt) acc[nt] = {0.f, 0.f, 0.f, 0.f};

  for (int kk = 0; kk < 4; ++kk) {
    __syncthreads();
#pragma unroll
    for (int p = 0; p < 2; ++p) {
      int e = p * 256 + t;
      int row = e >> 3, kg = e & 7;
      int lo = row * 72 + kg * 8;
      int gi_ = (base + i0 + row) * 256 + kk * 64 + kg * 8;
      *(uint4*)&Ah[lo] = *(const uint4*)&fnh[gi_];
      *(uint4*)&Al[lo] = *(const uint4*)&fnl[gi_];
      if (!diag) {
        int gj_ = (base + j0 + row) * 256 + kk * 64 + kg * 8;
        *(uint4*)&Bhh[lo] = *(const uint4*)&fnh[gj_];
        *(uint4*)&Bll[lo] = *(const uint4*)&fnl[gj_];
      }
    }
    __syncthreads();
#pragma unroll
    for (int ks = 0; ks < 2; ++ks) {
      int koff = ks * 32 + q * 8;           // ushort offset within row
      int arow = w * 16 + m;
      bf16x8 ah = *(const bf16x8*)&Ah[arow * 72 + koff];
      bf16x8 al = *(const bf16x8*)&Al[arow * 72 + koff];
#pragma unroll
      for (int nt = 0; nt < 4; ++nt) {
        bf16x8 bh = *(const bf16x8*)&Bh[(nt * 16 + m) * 72 + koff];
        bf16x8 bl = *(const bf16x8*)&Bl[(nt * 16 + m) * 72 + koff];
        acc[nt] = __builtin_amdgcn_mfma_f32_16x16x32_bf16(ah, bh, acc[nt], 0, 0, 0);
        acc[nt] = __builtin_amdgcn_mfma_f32_16x16x32_bf16(ah, bl, acc[nt], 0, 0, 0);
        acc[nt] = __builtin_amdgcn_mfma_f32_16x16x32_bf16(al, bh, acc[nt], 0, 0, 0);
      }
    }
  }

  // ---- epilogue ----
  // C/D layout (verified m89/m91): col = lane&15 (j), row = (lane>>4)*4+reg (i)
  int   gi[4], gj[4], si[4], sj[4], ci[4], cj[4];
  float twi[4], twj[4];
#pragma unroll
  for (int reg = 0; reg < 4; ++reg) {
    int i = i0 + w * 16 + q * 4 + reg;
    gi[reg] = i; twi[reg] = tw[base + i];
    si[reg] = selv[base + i]; ci[reg] = tsp[base + i];
  }
#pragma unroll
  for (int nt = 0; nt < 4; ++nt) {
    int j = j0 + nt * 16 + m;
    gj[nt] = j; twj[nt] = tw[base + j];
    sj[nt] = selv[base + j]; cj[nt] = tsp[base + j];
  }

  float dR[4] = {0, 0, 0, 0}, PR[4] = {0, 0, 0, 0};
  float dC[4] = {0, 0, 0, 0}, PC[4] = {0, 0, 0, 0};
  float Sp = 0.f;
#pragma unroll
  for (int nt = 0; nt < 4; ++nt) {
#pragma unroll
    for (int reg = 0; reg < 4; ++reg) {
      float s = acc[nt][reg];
      float e10 = __expf(s * INV_T);
      if (sj[nt]) dR[reg] += e10;
      if (si[reg]) dC[nt] += e10;
      if (si[reg] && sj[nt] && (ci[reg] == cj[nt]) && (s > THR) && (gi[reg] != gj[nt])) {
        float pw = twi[reg] * twj[nt];
        PR[reg] += pw;
        PC[nt] += pw;
        Sp += pw * s;
      }
    }
  }

  // row reduce across m (xor 1,2,4,8 stays within the 16-lane group)
  for (int off = 8; off > 0; off >>= 1) {
#pragma unroll
    for (int reg = 0; reg < 4; ++reg) {
      dR[reg] += __shfl_xor(dR[reg], off, 64);
      PR[reg] += __shfl_xor(PR[reg], off, 64);
    }
  }
  if (m == 0) {
#pragma unroll
    for (int reg = 0; reg < 4; ++reg) {
      drl[w * 16 + q * 4 + reg] = dR[reg];
      Prl[w * 16 + q * 4 + reg] = PR[reg];
    }
  }
  // col reduce across q (xor 16,32), then stash per-wave partials
  if (!diag) {
    for (int off = 32; off >= 16; off >>= 1) {
#pragma unroll
      for (int nt = 0; nt < 4; ++nt) {
        dC[nt] += __shfl_xor(dC[nt], off, 64);
        PC[nt] += __shfl_xor(PC[nt], off, 64);
      }
    }
    if (q == 0) {
#pragma unroll
      for (int nt = 0; nt < 4; ++nt) {
        dclw[w][nt * 16 + m] = dC[nt];
        Pclw[w][nt * 16 + m] = PC[nt];
      }
    }
  }
  // S reduce across full wave
  for (int off = 32; off > 0; off >>= 1) Sp += __shfl_xor(Sp, off, 64);
  if (lane == 0) swv[w] = Sp;
  __syncthreads();

  if (t < 64) {
    atomicAdd(&denom[base + i0 + t], drl[t]);
    atomicAdd(&Prow [base + i0 + t], Prl[t]);
    if (!diag) {
      float dc = dclw[0][t] + dclw[1][t] + dclw[2][t] + dclw[3][t];
      float pc = Pclw[0][t] + Pclw[1][t] + Pclw[2][t] + Pclw[3][t];
      atomicAdd(&denom[base + j0 + t], dc);
      atomicAdd(&Prow [base + j0 + t], pc);
    }
  }
  if (t == 0) {
    float St = swv[0] + swv[1] + swv[2] + swv[3];
    atomicAdd(&Ssum[b], diag ? St : 2.f * St);
  }
}

// ---------------------------------------------------------------------------
// Kernel 4: finalize. loss_b = -(T/BT) * (S_b/T - sum_i P_i log D_i) / psum_b
// ---------------------------------------------------------------------------
__global__ __launch_bounds__(1024) void finalize_kernel(
    const float* __restrict__ denom, const float* __restrict__ Prow,
    const float* __restrict__ Ssum, float* __restrict__ out) {
  int t = threadIdx.x;
  int b = t >> 8, u = t & 255;
  float P = 0.f, L = 0.f;
#pragma unroll
  for (int q = 0; q < 4; ++q) {
    int s = u + q * 256;
    float p = Prow[b * SSEL + s];
    float D = denom[b * SSEL + s];
    P += p;
    L += p * logf(D > 0.f ? D : 1.f);
  }
  for (int off = 32; off > 0; off >>= 1) {
    P += __shfl_xor(P, off, 64);
    L += __shfl_xor(L, off, 64);
  }
  __shared__ float wP[16], wL[16];
  int lane = t & 63, w = t >> 6;
  if (lane == 0) { wP[w] = P; wL[w] = L; }
  __syncthreads();
  if (t == 0) {
    float total = 0.f, n = 0.f;
    for (int bb = 0; bb < BATCH; ++bb) {
      float psum = wP[4 * bb] + wP[4 * bb + 1] + wP[4 * bb + 2] + wP[4 * bb + 3];
      float lsum = wL[4 * bb] + wL[4 * bb + 1] + wL[4 * bb + 2] + wL[4 * bb + 3];
      if (psum > 0.f) {
        float wls = Ssum[bb] * INV_T - lsum;
        total += -RATIO * wls / psum;
        n += 1.f;
      }
    }
    out[0] = (n > 0.f) ? (total / n) : 0.f;
  }
}

// ---------------------------------------------------------------------------
extern "C" void kernel_launch(void* const* d_in, const int* in_sizes, int n_in,
                              void* d_out, int out_size, void* d_ws, size_t ws_size,
                              hipStream_t stream) {
  const float* feats = (const float*)d_in[0];
  const int*   labels = (const int*)d_in[1];
  const int*   sp     = (const int*)d_in[2];
  const float* w1  = (const float*)d_in[3];
  const float* b1  = (const float*)d_in[4];
  const float* w2  = (const float*)d_in[5];
  const float* b2  = (const float*)d_in[6];
  const float* wa1 = (const float*)d_in[7];
  const float* ba1 = (const float*)d_in[8];
  const float* wa2 = (const float*)d_in[9];
  const float* ba2 = (const float*)d_in[10];
  float* out = (float*)d_out;

  float* W    = (float*)d_ws;
  float* w1p  = W;                      // 65536 f
  float* w2p  = w1p  + 65536;           // 65536 f
  float* wa1p = w2p  + 65536;           // 16384 f
  unsigned short* fnh = (unsigned short*)(wa1p + 16384);  // 1048576 us (16B-aligned)
  unsigned short* fnl = fnh + 1048576;                    // 1048576 us
  float* tw   = (float*)(fnl + 1048576);// 4096 f
  float* denom= tw   + 4096;            // 4096
  float* Prow = denom+ 4096;            // 4096
  float* Ssum = Prow + 4096;            // 4
  int*   idx  = (int*)(Ssum + 4);       // 4096
  int*   selv = idx  + 4096;            // 4096
  int*   tsp  = selv + 4096;            // 4096
  int*   counts = tsp + 4096;           // 100

  pack_weights<<<256, 256, 0, stream>>>(w1, w2, wa1, labels, w1p, w2p, wa1p,
                                        denom, Prow, Ssum, counts);
  select_scatter<<<BATCH * NCHUNK, 1024, 0, stream>>>(labels, sp, counts,
                                                      idx, selv, tsp);
  mlp_kernel<<<(BATCH * SSEL) / RROWS, 256, 0, stream>>>(
      feats, w1p, b1, w2p, b2, wa1p, ba1, wa2, ba2, idx, fnh, fnl, tw);
  sim_kernel<<<dim3(136, BATCH), 256, 0, stream>>>(fnh, fnl, tw, selv, tsp,
                                                   denom, Prow, Ssum);
  finalize_kernel<<<1, 1024, 0, stream>>>(denom, Prow, Ssum, out);
}

// Round 6
// 195.803 us; speedup vs baseline: 1.1855x; 1.1855x over previous
//
#include <hip/hip_runtime.h>
#include <hip/hip_bf16.h>
#include <math.h>

// Problem constants
#define NPIX   25600      // H*W = 160*160
#define CDIM   256
#define SSEL   1024       // MAX_SAMPLES
#define BATCH  4
#define NCHUNK 25         // NPIX / 1024
#define INV_T  10.0f      // 1/TEMP
#define RATIO  1.4285714285714286f  // TEMP/BASE_TEMP
#define THR    0.7f

typedef __attribute__((ext_vector_type(8))) short bf16x8;
typedef __attribute__((ext_vector_type(4))) float f32x4;
typedef unsigned short u16;

__device__ __forceinline__ void bf16_split(float v, u16& h, u16& l) {
  __hip_bfloat16 hb = __float2bfloat16(v);
  __hip_bfloat16 lb = __float2bfloat16(v - __bfloat162float(hb));
  h = *reinterpret_cast<u16*>(&hb);
  l = *reinterpret_cast<u16*>(&lb);
}

// ---------------------------------------------------------------------------
// Kernel 0: weights fp32 -> split bf16 (plain [out][in] layout) + zero
// accumulators + per-chunk valid counts.
// ---------------------------------------------------------------------------
__global__ __launch_bounds__(256) void pack_weights(
    const float* __restrict__ w1, const float* __restrict__ w2,
    const float* __restrict__ wa1, const int* __restrict__ labels,
    u16* __restrict__ w1hb, u16* __restrict__ w1lb,
    u16* __restrict__ w2hb, u16* __restrict__ w2lb,
    u16* __restrict__ wahb, u16* __restrict__ walb,
    float* __restrict__ denom, float* __restrict__ Prow, float* __restrict__ Ssum,
    float* __restrict__ nrm, int* __restrict__ counts) {
  int t = threadIdx.x;
  int e = blockIdx.x * 256 + t;
  if (e < 65536) {
    bf16_split(w1[e], w1hb[e], w1lb[e]);
    bf16_split(w2[e], w2hb[e], w2lb[e]);
  }
  if (e < 16384) bf16_split(wa1[e], wahb[e], walb[e]);
  if (e < BATCH * SSEL) { denom[e] = 0.f; Prow[e] = 0.f; nrm[e] = 0.f; }
  if (e < BATCH) Ssum[e] = 0.f;

  if (blockIdx.x < BATCH * NCHUNK) {
    int b = blockIdx.x / NCHUNK, ch = blockIdx.x % NCHUNK;
    const int* lab = labels + b * NPIX + ch * 1024;
    int local = 0;
#pragma unroll
    for (int qq = 0; qq < 4; ++qq) local += (lab[qq * 256 + t] == 1);
    for (int off = 32; off > 0; off >>= 1) local += __shfl_xor(local, off, 64);
    __shared__ int ws[4];
    if ((t & 63) == 0) ws[t >> 6] = local;
    __syncthreads();
    if (t == 0) counts[blockIdx.x] = ws[0] + ws[1] + ws[2] + ws[3];
  }
}

// ---------------------------------------------------------------------------
// Kernel 1: stable scatter ("valid first" order, first 1024 slots).
// ---------------------------------------------------------------------------
__global__ __launch_bounds__(1024) void select_scatter(
    const int* __restrict__ labels, const int* __restrict__ sp,
    const int* __restrict__ counts,
    int* __restrict__ idx, int* __restrict__ selv, int* __restrict__ tsp) {
  int b = blockIdx.x / NCHUNK, ch = blockIdx.x % NCHUNK;
  int t = threadIdx.x;
  __shared__ int cs[NCHUNK];
  __shared__ int wave_tot[16];
  if (t < NCHUNK) cs[t] = counts[b * NCHUNK + t];
  __syncthreads();
  int Vtot = 0, vbase = 0;
#pragma unroll
  for (int c = 0; c < NCHUNK; ++c) {
    int v = cs[c];
    Vtot += v;
    if (c < ch) vbase += v;
  }
  int ibase = ch * 1024 - vbase;

  int i = ch * 1024 + t;
  int isv = (labels[b * NPIX + i] == 1) ? 1 : 0;
  int lane = t & 63, wid = t >> 6;
  unsigned long long mv = __ballot(isv);
  int pv = __popcll(mv & ((1ull << lane) - 1ull));
  if (lane == 0) wave_tot[wid] = __popcll(mv);
  __syncthreads();
  for (int w = 0; w < wid; ++w) pv += wave_tot[w];
  int gslot = isv ? (vbase + pv) : (Vtot + ibase + (t - pv));
  if (gslot < SSEL) {
    idx [b * SSEL + gslot] = i;
    selv[b * SSEL + gslot] = isv;
    tsp [b * SSEL + gslot] = sp[b * NPIX + i];
  }
}

// ---------------------------------------------------------------------------
// Kernel 2: gather selected pixels -> packed split-bf16 x [4096 x 256].
// thread = channel (coalesced-ish writes); scattered reads L1/L2-absorbed
// (selected pixels are index-sorted, ~8 per cache line).
// ---------------------------------------------------------------------------
__global__ __launch_bounds__(256) void gather_cast(
    const float* __restrict__ feats, const int* __restrict__ idx,
    u16* __restrict__ xh, u16* __restrict__ xl) {
  int r0 = blockIdx.x * 16;
  int b  = r0 >> 10;
  int t  = threadIdx.x;
  __shared__ int ridx[16];
  if (t < 16) ridx[t] = idx[r0 + t];
  __syncthreads();
  const float* fb = feats + ((long)b * CDIM + t) * NPIX;
#pragma unroll 4
  for (int r = 0; r < 16; ++r) {
    float v = fb[ridx[r]];
    u16 h, l;
    bf16_split(v, h, l);
    long o = (long)(r0 + r) * CDIM + t;
    xh[o] = h;
    xl[o] = l;
  }
}

// ---------------------------------------------------------------------------
// Kernel 3: layer1 GEMM (split-bf16 MFMA): h = relu(x @ w1.T + b1), written
// as split bf16. Col-tile n==4 is the fused attn path: relu(x@wa1.T+ba1)
// dot wa2 + ba2 -> sigmoid -> tw.
// Grid (5, 64); 64x64 tile per block, 4 waves.
// ---------------------------------------------------------------------------
__global__ __launch_bounds__(256) void gemm1_kernel(
    const u16* __restrict__ xh, const u16* __restrict__ xl,
    const u16* __restrict__ w1hb, const u16* __restrict__ w1lb,
    const u16* __restrict__ wahb, const u16* __restrict__ walb,
    const float* __restrict__ b1, const float* __restrict__ ba1,
    const float* __restrict__ wa2, const float* __restrict__ ba2,
    u16* __restrict__ hh, u16* __restrict__ hl, float* __restrict__ tw) {
  int n  = blockIdx.x;          // 0..3 = w1 col tiles, 4 = attn
  int i0 = blockIdx.y * 64;
  int t = threadIdx.x;
  int lane = t & 63, w = t >> 6, m = lane & 15, q = lane >> 4;
  bool attn = (n == 4);
  const u16* bsh = attn ? wahb : (w1hb + n * 64 * 256);
  const u16* bsl = attn ? walb : (w1lb + n * 64 * 256);

  __shared__ __align__(16) u16 Ah[64 * 72], Al[64 * 72];
  __shared__ __align__(16) u16 Bh[64 * 72], Bl[64 * 72];

  f32x4 acc[4];
#pragma unroll
  for (int nt = 0; nt < 4; ++nt) acc[nt] = {0.f, 0.f, 0.f, 0.f};

  for (int kk = 0; kk < 4; ++kk) {
    __syncthreads();
#pragma unroll
    for (int p = 0; p < 2; ++p) {
      int e = p * 256 + t;
      int row = e >> 3, kg = e & 7;
      int lo = row * 72 + kg * 8;
      int go = row * 256 + kk * 64 + kg * 8;
      *(uint4*)&Ah[lo] = *(const uint4*)&xh[(i0 + row) * 256 + kk * 64 + kg * 8];
      *(uint4*)&Al[lo] = *(const uint4*)&xl[(i0 + row) * 256 + kk * 64 + kg * 8];
      *(uint4*)&Bh[lo] = *(const uint4*)&bsh[go];
      *(uint4*)&Bl[lo] = *(const uint4*)&bsl[go];
    }
    __syncthreads();
#pragma unroll
    for (int ks = 0; ks < 2; ++ks) {
      int koff = ks * 32 + q * 8;
      bf16x8 ah = *(const bf16x8*)&Ah[(w * 16 + m) * 72 + koff];
      bf16x8 al = *(const bf16x8*)&Al[(w * 16 + m) * 72 + koff];
#pragma unroll
      for (int nt = 0; nt < 4; ++nt) {
        bf16x8 bh = *(const bf16x8*)&Bh[(nt * 16 + m) * 72 + koff];
        bf16x8 bl = *(const bf16x8*)&Bl[(nt * 16 + m) * 72 + koff];
        acc[nt] = __builtin_amdgcn_mfma_f32_16x16x32_bf16(ah, bh, acc[nt], 0, 0, 0);
        acc[nt] = __builtin_amdgcn_mfma_f32_16x16x32_bf16(ah, bl, acc[nt], 0, 0, 0);
        acc[nt] = __builtin_amdgcn_mfma_f32_16x16x32_bf16(al, bh, acc[nt], 0, 0, 0);
      }
    }
  }

  // C/D layout: col = lane&15 (m), row = q*4 + reg
  if (!attn) {
#pragma unroll
    for (int nt = 0; nt < 4; ++nt) {
      int col = n * 64 + nt * 16 + m;
      float bb = b1[col];
#pragma unroll
      for (int reg = 0; reg < 4; ++reg) {
        int row = i0 + w * 16 + q * 4 + reg;
        float v = fmaxf(acc[nt][reg] + bb, 0.f);
        u16 h, l;
        bf16_split(v, h, l);
        hh[row * 256 + col] = h;
        hl[row * 256 + col] = l;
      }
    }
  } else {
    float part[4] = {0.f, 0.f, 0.f, 0.f};
#pragma unroll
    for (int nt = 0; nt < 4; ++nt) {
      int ca = nt * 16 + m;
      float bb = ba1[ca], wv = wa2[ca];
#pragma unroll
      for (int reg = 0; reg < 4; ++reg)
        part[reg] += fmaxf(acc[nt][reg] + bb, 0.f) * wv;
    }
    for (int off = 8; off > 0; off >>= 1) {
#pragma unroll
      for (int reg = 0; reg < 4; ++reg)
        part[reg] += __shfl_xor(part[reg], off, 64);
    }
    if (m == 0) {
      float bb2 = ba2[0];
#pragma unroll
      for (int reg = 0; reg < 4; ++reg) {
        int row = i0 + w * 16 + q * 4 + reg;
        tw[row] = 1.f / (1.f + expf(-(part[reg] + bb2)));
      }
    }
  }
}

// ---------------------------------------------------------------------------
// Kernel 4: layer2 GEMM (split-bf16 MFMA): p = h @ w2.T + b2 -> pbuf fp32,
// plus atomic row sum-of-squares into nrm. Grid (4, 64).
// ---------------------------------------------------------------------------
__global__ __launch_bounds__(256) void gemm2_kernel(
    const u16* __restrict__ hh, const u16* __restrict__ hl,
    const u16* __restrict__ w2hb, const u16* __restrict__ w2lb,
    const float* __restrict__ b2,
    float* __restrict__ pbuf, float* __restrict__ nrm) {
  int n  = blockIdx.x;          // 0..3
  int i0 = blockIdx.y * 64;
  int t = threadIdx.x;
  int lane = t & 63, w = t >> 6, m = lane & 15, q = lane >> 4;
  const u16* bsh = w2hb + n * 64 * 256;
  const u16* bsl = w2lb + n * 64 * 256;

  __shared__ __align__(16) u16 Ah[64 * 72], Al[64 * 72];
  __shared__ __align__(16) u16 Bh[64 * 72], Bl[64 * 72];

  f32x4 acc[4];
#pragma unroll
  for (int nt = 0; nt < 4; ++nt) acc[nt] = {0.f, 0.f, 0.f, 0.f};

  for (int kk = 0; kk < 4; ++kk) {
    __syncthreads();
#pragma unroll
    for (int p = 0; p < 2; ++p) {
      int e = p * 256 + t;
      int row = e >> 3, kg = e & 7;
      int lo = row * 72 + kg * 8;
      int go = row * 256 + kk * 64 + kg * 8;
      *(uint4*)&Ah[lo] = *(const uint4*)&hh[(i0 + row) * 256 + kk * 64 + kg * 8];
      *(uint4*)&Al[lo] = *(const uint4*)&hl[(i0 + row) * 256 + kk * 64 + kg * 8];
      *(uint4*)&Bh[lo] = *(const uint4*)&bsh[go];
      *(uint4*)&Bl[lo] = *(const uint4*)&bsl[go];
    }
    __syncthreads();
#pragma unroll
    for (int ks = 0; ks < 2; ++ks) {
      int koff = ks * 32 + q * 8;
      bf16x8 ah = *(const bf16x8*)&Ah[(w * 16 + m) * 72 + koff];
      bf16x8 al = *(const bf16x8*)&Al[(w * 16 + m) * 72 + koff];
#pragma unroll
      for (int nt = 0; nt < 4; ++nt) {
        bf16x8 bh = *(const bf16x8*)&Bh[(nt * 16 + m) * 72 + koff];
        bf16x8 bl = *(const bf16x8*)&Bl[(nt * 16 + m) * 72 + koff];
        acc[nt] = __builtin_amdgcn_mfma_f32_16x16x32_bf16(ah, bh, acc[nt], 0, 0, 0);
        acc[nt] = __builtin_amdgcn_mfma_f32_16x16x32_bf16(ah, bl, acc[nt], 0, 0, 0);
        acc[nt] = __builtin_amdgcn_mfma_f32_16x16x32_bf16(al, bh, acc[nt], 0, 0, 0);
      }
    }
  }

  float part[4] = {0.f, 0.f, 0.f, 0.f};
#pragma unroll
  for (int nt = 0; nt < 4; ++nt) {
    int col = n * 64 + nt * 16 + m;
    float bb = b2[col];
#pragma unroll
    for (int reg = 0; reg < 4; ++reg) {
      int row = i0 + w * 16 + q * 4 + reg;
      float p = acc[nt][reg] + bb;
      pbuf[row * 256 + col] = p;
      part[reg] += p * p;
    }
  }
  for (int off = 8; off > 0; off >>= 1) {
#pragma unroll
    for (int reg = 0; reg < 4; ++reg)
      part[reg] += __shfl_xor(part[reg], off, 64);
  }
  if (m == 0) {
#pragma unroll
    for (int reg = 0; reg < 4; ++reg) {
      int row = i0 + w * 16 + q * 4 + reg;
      atomicAdd(&nrm[row], part[reg]);
    }
  }
}

// ---------------------------------------------------------------------------
// Kernel 5: normalize rows of pbuf and emit split-bf16 fn planes.
// thread = 8 contiguous elements. Grid 512 x 256.
// ---------------------------------------------------------------------------
__global__ __launch_bounds__(256) void norm_split(
    const float* __restrict__ pbuf, const float* __restrict__ nrm,
    u16* __restrict__ fnh, u16* __restrict__ fnl) {
  int e = blockIdx.x * 256 + threadIdx.x;   // 0..131071
  long base = (long)e * 8;
  int row = e >> 5;
  float inv = 1.f / fmaxf(sqrtf(nrm[row]), 1e-12f);
  float4 pa = *(const float4*)&pbuf[base];
  float4 pb = *(const float4*)&pbuf[base + 4];
  float v[8] = {pa.x, pa.y, pa.z, pa.w, pb.x, pb.y, pb.z, pb.w};
  u16 hs[8], ls[8];
#pragma unroll
  for (int j = 0; j < 8; ++j) bf16_split(v[j] * inv, hs[j], ls[j]);
  *(uint4*)&fnh[base] = *(const uint4*)hs;
  *(uint4*)&fnl[base] = *(const uint4*)ls;
}

// ---------------------------------------------------------------------------
// Kernel 6: MFMA sim = fn @ fn.T (split-bf16). Triangular tiles tj>=ti.
// ---------------------------------------------------------------------------
__global__ __launch_bounds__(256) void sim_kernel(
    const u16* __restrict__ fnh, const u16* __restrict__ fnl,
    const float* __restrict__ tw,
    const int* __restrict__ selv, const int* __restrict__ tsp,
    float* __restrict__ denom, float* __restrict__ Prow, float* __restrict__ Ssum) {
  int b = blockIdx.y;
  int t = threadIdx.x;
  int lane = t & 63, w = t >> 6;
  int m = lane & 15, q = lane >> 4;

  int rem = blockIdx.x, ti = 0;
  while (rem >= (16 - ti)) { rem -= (16 - ti); ++ti; }
  int tj = ti + rem;
  bool diag = (ti == tj);
  int i0 = ti * 64, j0 = tj * 64;
  int base = b << 10;

  __shared__ __align__(16) u16 Ah[64 * 72], Al[64 * 72];
  __shared__ __align__(16) u16 Bhh[64 * 72], Bll[64 * 72];
  __shared__ float drl[64], Prl[64];
  __shared__ float dclw[4][64], Pclw[4][64];
  __shared__ float swv[4];

  const u16* Bh = diag ? Ah : Bhh;
  const u16* Bl = diag ? Al : Bll;

  f32x4 acc[4];
#pragma unroll
  for (int nt = 0; nt < 4; ++nt) acc[nt] = {0.f, 0.f, 0.f, 0.f};

  for (int kk = 0; kk < 4; ++kk) {
    __syncthreads();
#pragma unroll
    for (int p = 0; p < 2; ++p) {
      int e = p * 256 + t;
      int row = e >> 3, kg = e & 7;
      int lo = row * 72 + kg * 8;
      int gi_ = (base + i0 + row) * 256 + kk * 64 + kg * 8;
      *(uint4*)&Ah[lo] = *(const uint4*)&fnh[gi_];
      *(uint4*)&Al[lo] = *(const uint4*)&fnl[gi_];
      if (!diag) {
        int gj_ = (base + j0 + row) * 256 + kk * 64 + kg * 8;
        *(uint4*)&Bhh[lo] = *(const uint4*)&fnh[gj_];
        *(uint4*)&Bll[lo] = *(const uint4*)&fnl[gj_];
      }
    }
    __syncthreads();
#pragma unroll
    for (int ks = 0; ks < 2; ++ks) {
      int koff = ks * 32 + q * 8;
      int arow = w * 16 + m;
      bf16x8 ah = *(const bf16x8*)&Ah[arow * 72 + koff];
      bf16x8 al = *(const bf16x8*)&Al[arow * 72 + koff];
#pragma unroll
      for (int nt = 0; nt < 4; ++nt) {
        bf16x8 bh = *(const bf16x8*)&Bh[(nt * 16 + m) * 72 + koff];
        bf16x8 bl = *(const bf16x8*)&Bl[(nt * 16 + m) * 72 + koff];
        acc[nt] = __builtin_amdgcn_mfma_f32_16x16x32_bf16(ah, bh, acc[nt], 0, 0, 0);
        acc[nt] = __builtin_amdgcn_mfma_f32_16x16x32_bf16(ah, bl, acc[nt], 0, 0, 0);
        acc[nt] = __builtin_amdgcn_mfma_f32_16x16x32_bf16(al, bh, acc[nt], 0, 0, 0);
      }
    }
  }

  int   gi[4], gj[4], si[4], sj[4], ci[4], cj[4];
  float twi[4], twj[4];
#pragma unroll
  for (int reg = 0; reg < 4; ++reg) {
    int i = i0 + w * 16 + q * 4 + reg;
    gi[reg] = i; twi[reg] = tw[base + i];
    si[reg] = selv[base + i]; ci[reg] = tsp[base + i];
  }
#pragma unroll
  for (int nt = 0; nt < 4; ++nt) {
    int j = j0 + nt * 16 + m;
    gj[nt] = j; twj[nt] = tw[base + j];
    sj[nt] = selv[base + j]; cj[nt] = tsp[base + j];
  }

  float dR[4] = {0, 0, 0, 0}, PR[4] = {0, 0, 0, 0};
  float dC[4] = {0, 0, 0, 0}, PC[4] = {0, 0, 0, 0};
  float Sp = 0.f;
#pragma unroll
  for (int nt = 0; nt < 4; ++nt) {
#pragma unroll
    for (int reg = 0; reg < 4; ++reg) {
      float s = acc[nt][reg];
      float e10 = __expf(s * INV_T);
      if (sj[nt]) dR[reg] += e10;
      if (si[reg]) dC[nt] += e10;
      if (si[reg] && sj[nt] && (ci[reg] == cj[nt]) && (s > THR) && (gi[reg] != gj[nt])) {
        float pw = twi[reg] * twj[nt];
        PR[reg] += pw;
        PC[nt] += pw;
        Sp += pw * s;
      }
    }
  }

  for (int off = 8; off > 0; off >>= 1) {
#pragma unroll
    for (int reg = 0; reg < 4; ++reg) {
      dR[reg] += __shfl_xor(dR[reg], off, 64);
      PR[reg] += __shfl_xor(PR[reg], off, 64);
    }
  }
  if (m == 0) {
#pragma unroll
    for (int reg = 0; reg < 4; ++reg) {
      drl[w * 16 + q * 4 + reg] = dR[reg];
      Prl[w * 16 + q * 4 + reg] = PR[reg];
    }
  }
  if (!diag) {
    for (int off = 32; off >= 16; off >>= 1) {
#pragma unroll
      for (int nt = 0; nt < 4; ++nt) {
        dC[nt] += __shfl_xor(dC[nt], off, 64);
        PC[nt] += __shfl_xor(PC[nt], off, 64);
      }
    }
    if (q == 0) {
#pragma unroll
      for (int nt = 0; nt < 4; ++nt) {
        dclw[w][nt * 16 + m] = dC[nt];
        Pclw[w][nt * 16 + m] = PC[nt];
      }
    }
  }
  for (int off = 32; off > 0; off >>= 1) Sp += __shfl_xor(Sp, off, 64);
  if (lane == 0) swv[w] = Sp;
  __syncthreads();

  if (t < 64) {
    atomicAdd(&denom[base + i0 + t], drl[t]);
    atomicAdd(&Prow [base + i0 + t], Prl[t]);
    if (!diag) {
      float dc = dclw[0][t] + dclw[1][t] + dclw[2][t] + dclw[3][t];
      float pc = Pclw[0][t] + Pclw[1][t] + Pclw[2][t] + Pclw[3][t];
      atomicAdd(&denom[base + j0 + t], dc);
      atomicAdd(&Prow [base + j0 + t], pc);
    }
  }
  if (t == 0) {
    float St = swv[0] + swv[1] + swv[2] + swv[3];
    atomicAdd(&Ssum[b], diag ? St : 2.f * St);
  }
}

// ---------------------------------------------------------------------------
// Kernel 7: finalize. loss_b = -(T/BT) * (S_b/T - sum_i P_i log D_i) / psum_b
// ---------------------------------------------------------------------------
__global__ __launch_bounds__(1024) void finalize_kernel(
    const float* __restrict__ denom, const float* __restrict__ Prow,
    const float* __restrict__ Ssum, float* __restrict__ out) {
  int t = threadIdx.x;
  int b = t >> 8, u = t & 255;
  float P = 0.f, L = 0.f;
#pragma unroll
  for (int q = 0; q < 4; ++q) {
    int s = u + q * 256;
    float p = Prow[b * SSEL + s];
    float D = denom[b * SSEL + s];
    P += p;
    L += p * logf(D > 0.f ? D : 1.f);
  }
  for (int off = 32; off > 0; off >>= 1) {
    P += __shfl_xor(P, off, 64);
    L += __shfl_xor(L, off, 64);
  }
  __shared__ float wP[16], wL[16];
  int lane = t & 63, w = t >> 6;
  if (lane == 0) { wP[w] = P; wL[w] = L; }
  __syncthreads();
  if (t == 0) {
    float total = 0.f, n = 0.f;
    for (int bb = 0; bb < BATCH; ++bb) {
      float psum = wP[4 * bb] + wP[4 * bb + 1] + wP[4 * bb + 2] + wP[4 * bb + 3];
      float lsum = wL[4 * bb] + wL[4 * bb + 1] + wL[4 * bb + 2] + wL[4 * bb + 3];
      if (psum > 0.f) {
        float wls = Ssum[bb] * INV_T - lsum;
        total += -RATIO * wls / psum;
        n += 1.f;
      }
    }
    out[0] = (n > 0.f) ? (total / n) : 0.f;
  }
}

// ---------------------------------------------------------------------------
extern "C" void kernel_launch(void* const* d_in, const int* in_sizes, int n_in,
                              void* d_out, int out_size, void* d_ws, size_t ws_size,
                              hipStream_t stream) {
  const float* feats = (const float*)d_in[0];
  const int*   labels = (const int*)d_in[1];
  const int*   sp     = (const int*)d_in[2];
  const float* w1  = (const float*)d_in[3];
  const float* b1  = (const float*)d_in[4];
  const float* w2  = (const float*)d_in[5];
  const float* b2  = (const float*)d_in[6];
  const float* wa1 = (const float*)d_in[7];
  const float* ba1 = (const float*)d_in[8];
  const float* wa2 = (const float*)d_in[9];
  const float* ba2 = (const float*)d_in[10];
  float* out = (float*)d_out;

  char* W = (char*)d_ws;
  u16* w1hb = (u16*)W;               W += 65536 * 2;
  u16* w1lb = (u16*)W;               W += 65536 * 2;
  u16* w2hb = (u16*)W;               W += 65536 * 2;
  u16* w2lb = (u16*)W;               W += 65536 * 2;
  u16* wahb = (u16*)W;               W += 16384 * 2;
  u16* walb = (u16*)W;               W += 16384 * 2;
  u16* xh   = (u16*)W;               W += 1048576 * 2;
  u16* xl   = (u16*)W;               W += 1048576 * 2;
  u16* hh   = (u16*)W;               W += 1048576 * 2;
  u16* hl   = (u16*)W;               W += 1048576 * 2;
  u16* fnh  = (u16*)W;               W += 1048576 * 2;
  u16* fnl  = (u16*)W;               W += 1048576 * 2;
  float* pbuf = (float*)W;           W += 1048576 * 4;
  float* nrm  = (float*)W;           W += 4096 * 4;
  float* tw   = (float*)W;           W += 4096 * 4;
  float* denom= (float*)W;           W += 4096 * 4;
  float* Prow = (float*)W;           W += 4096 * 4;
  float* Ssum = (float*)W;           W += 4 * 4;
  int*   idx  = (int*)W;             W += 4096 * 4;
  int*   selv = (int*)W;             W += 4096 * 4;
  int*   tsp  = (int*)W;             W += 4096 * 4;
  int*   counts = (int*)W;           W += 128 * 4;

  pack_weights<<<256, 256, 0, stream>>>(w1, w2, wa1, labels,
                                        w1hb, w1lb, w2hb, w2lb, wahb, walb,
                                        denom, Prow, Ssum, nrm, counts);
  select_scatter<<<BATCH * NCHUNK, 1024, 0, stream>>>(labels, sp, counts,
                                                      idx, selv, tsp);
  gather_cast<<<256, 256, 0, stream>>>(feats, idx, xh, xl);
  gemm1_kernel<<<dim3(5, 64), 256, 0, stream>>>(xh, xl, w1hb, w1lb, wahb, walb,
                                                b1, ba1, wa2, ba2, hh, hl, tw);
  gemm2_kernel<<<dim3(4, 64), 256, 0, stream>>>(hh, hl, w2hb, w2lb, b2,
                                                pbuf, nrm);
  norm_split<<<512, 256, 0, stream>>>(pbuf, nrm, fnh, fnl);
  sim_kernel<<<dim3(136, BATCH), 256, 0, stream>>>(fnh, fnl, tw, selv, tsp,
                                                   denom, Prow, Ssum);
  finalize_kernel<<<1, 1024, 0, stream>>>(denom, Prow, Ssum, out);
}

// Round 7
// 194.865 us; speedup vs baseline: 1.1912x; 1.0048x over previous
//
#include <hip/hip_runtime.h>
#include <hip/hip_bf16.h>
#include <math.h>

// Problem constants
#define NPIX   25600      // H*W = 160*160
#define CDIM   256
#define SSEL   1024       // MAX_SAMPLES
#define BATCH  4
#define NCHUNK 25         // NPIX / 1024
#define INV_T  10.0f      // 1/TEMP
#define RATIO  1.4285714285714286f  // TEMP/BASE_TEMP
#define THR    0.7f

typedef __attribute__((ext_vector_type(8))) short bf16x8;
typedef __attribute__((ext_vector_type(4))) float f32x4;
typedef unsigned short u16;

__device__ __forceinline__ u16 to_bf16(float v) {
  __hip_bfloat16 h = __float2bfloat16(v);
  return *reinterpret_cast<u16*>(&h);
}

// ---------------------------------------------------------------------------
// Kernel 0: weights fp32 -> bf16 ([out][in] row-major) + zero accumulators +
// per-chunk valid counts.
// ---------------------------------------------------------------------------
__global__ __launch_bounds__(256) void pack_weights(
    const float* __restrict__ w1, const float* __restrict__ w2,
    const float* __restrict__ wa1, const int* __restrict__ labels,
    u16* __restrict__ w1b, u16* __restrict__ w2b, u16* __restrict__ wab,
    float* __restrict__ denom, float* __restrict__ Prow, float* __restrict__ Ssum,
    int* __restrict__ counts) {
  int t = threadIdx.x;
  int e = blockIdx.x * 256 + t;
  if (e < 65536) {
    w1b[e] = to_bf16(w1[e]);
    w2b[e] = to_bf16(w2[e]);
  }
  if (e < 16384) wab[e] = to_bf16(wa1[e]);
  if (e < BATCH * SSEL) { denom[e] = 0.f; Prow[e] = 0.f; }
  if (e < BATCH) Ssum[e] = 0.f;

  if (blockIdx.x < BATCH * NCHUNK) {
    int b = blockIdx.x / NCHUNK, ch = blockIdx.x % NCHUNK;
    const int* lab = labels + b * NPIX + ch * 1024;
    int local = 0;
#pragma unroll
    for (int qq = 0; qq < 4; ++qq) local += (lab[qq * 256 + t] == 1);
    for (int off = 32; off > 0; off >>= 1) local += __shfl_xor(local, off, 64);
    __shared__ int ws[4];
    if ((t & 63) == 0) ws[t >> 6] = local;
    __syncthreads();
    if (t == 0) counts[blockIdx.x] = ws[0] + ws[1] + ws[2] + ws[3];
  }
}

// ---------------------------------------------------------------------------
// Kernel 1: stable scatter ("valid first" order, first 1024 slots).
// ---------------------------------------------------------------------------
__global__ __launch_bounds__(1024) void select_scatter(
    const int* __restrict__ labels, const int* __restrict__ sp,
    const int* __restrict__ counts,
    int* __restrict__ idx, int* __restrict__ selv, int* __restrict__ tsp) {
  int b = blockIdx.x / NCHUNK, ch = blockIdx.x % NCHUNK;
  int t = threadIdx.x;
  __shared__ int cs[NCHUNK];
  __shared__ int wave_tot[16];
  if (t < NCHUNK) cs[t] = counts[b * NCHUNK + t];
  __syncthreads();
  int Vtot = 0, vbase = 0;
#pragma unroll
  for (int c = 0; c < NCHUNK; ++c) {
    int v = cs[c];
    Vtot += v;
    if (c < ch) vbase += v;
  }
  int ibase = ch * 1024 - vbase;

  int i = ch * 1024 + t;
  int isv = (labels[b * NPIX + i] == 1) ? 1 : 0;
  int lane = t & 63, wid = t >> 6;
  unsigned long long mv = __ballot(isv);
  int pv = __popcll(mv & ((1ull << lane) - 1ull));
  if (lane == 0) wave_tot[wid] = __popcll(mv);
  __syncthreads();
  for (int w = 0; w < wid; ++w) pv += wave_tot[w];
  int gslot = isv ? (vbase + pv) : (Vtot + ibase + (t - pv));
  if (gslot < SSEL) {
    idx [b * SSEL + gslot] = i;
    selv[b * SSEL + gslot] = isv;
    tsp [b * SSEL + gslot] = sp[b * NPIX + i];
  }
}

// ---------------------------------------------------------------------------
// Kernel 2: gather selected pixels -> packed bf16 x [4096 x 256].
// ---------------------------------------------------------------------------
__global__ __launch_bounds__(256) void gather_cast(
    const float* __restrict__ feats, const int* __restrict__ idx,
    u16* __restrict__ xh) {
  int r0 = blockIdx.x * 16;
  int b  = r0 >> 10;
  int t  = threadIdx.x;
  __shared__ int ridx[16];
  if (t < 16) ridx[t] = idx[r0 + t];
  __syncthreads();
  const float* fb = feats + ((long)b * CDIM + t) * NPIX;
#pragma unroll 4
  for (int r = 0; r < 16; ++r) {
    xh[(long)(r0 + r) * CDIM + t] = to_bf16(fb[ridx[r]]);
  }
}

// ---------------------------------------------------------------------------
// Kernel 3: layer1 GEMM (bf16 MFMA): h = relu(x @ w1.T + b1) -> bf16.
// Col-tile n==4 is the fused attn head -> tw. Grid (5, 64).
// ---------------------------------------------------------------------------
__global__ __launch_bounds__(256) void gemm1_kernel(
    const u16* __restrict__ xh, const u16* __restrict__ w1b,
    const u16* __restrict__ wab,
    const float* __restrict__ b1, const float* __restrict__ ba1,
    const float* __restrict__ wa2, const float* __restrict__ ba2,
    u16* __restrict__ hh, float* __restrict__ tw) {
  int n  = blockIdx.x;          // 0..3 = w1 col tiles, 4 = attn
  int i0 = blockIdx.y * 64;
  int t = threadIdx.x;
  int lane = t & 63, w = t >> 6, m = lane & 15, q = lane >> 4;
  bool attn = (n == 4);
  const u16* bsrc = attn ? wab : (w1b + n * 64 * 256);

  __shared__ __align__(16) u16 Ah[64 * 72];
  __shared__ __align__(16) u16 Bh[64 * 72];

  f32x4 acc[4];
#pragma unroll
  for (int nt = 0; nt < 4; ++nt) acc[nt] = {0.f, 0.f, 0.f, 0.f};

  for (int kk = 0; kk < 4; ++kk) {
    __syncthreads();
#pragma unroll
    for (int p = 0; p < 2; ++p) {
      int e = p * 256 + t;
      int row = e >> 3, kg = e & 7;
      int lo = row * 72 + kg * 8;
      *(uint4*)&Ah[lo] = *(const uint4*)&xh[(i0 + row) * 256 + kk * 64 + kg * 8];
      *(uint4*)&Bh[lo] = *(const uint4*)&bsrc[row * 256 + kk * 64 + kg * 8];
    }
    __syncthreads();
#pragma unroll
    for (int ks = 0; ks < 2; ++ks) {
      int koff = ks * 32 + q * 8;
      bf16x8 ah = *(const bf16x8*)&Ah[(w * 16 + m) * 72 + koff];
#pragma unroll
      for (int nt = 0; nt < 4; ++nt) {
        bf16x8 bh = *(const bf16x8*)&Bh[(nt * 16 + m) * 72 + koff];
        acc[nt] = __builtin_amdgcn_mfma_f32_16x16x32_bf16(ah, bh, acc[nt], 0, 0, 0);
      }
    }
  }

  // C/D layout: col = lane&15 (m), row = q*4 + reg
  if (!attn) {
#pragma unroll
    for (int nt = 0; nt < 4; ++nt) {
      int col = n * 64 + nt * 16 + m;
      float bb = b1[col];
#pragma unroll
      for (int reg = 0; reg < 4; ++reg) {
        int row = i0 + w * 16 + q * 4 + reg;
        hh[row * 256 + col] = to_bf16(fmaxf(acc[nt][reg] + bb, 0.f));
      }
    }
  } else {
    float part[4] = {0.f, 0.f, 0.f, 0.f};
#pragma unroll
    for (int nt = 0; nt < 4; ++nt) {
      int ca = nt * 16 + m;
      float bb = ba1[ca], wv = wa2[ca];
#pragma unroll
      for (int reg = 0; reg < 4; ++reg)
        part[reg] += fmaxf(acc[nt][reg] + bb, 0.f) * wv;
    }
    for (int off = 8; off > 0; off >>= 1) {
#pragma unroll
      for (int reg = 0; reg < 4; ++reg)
        part[reg] += __shfl_xor(part[reg], off, 64);
    }
    if (m == 0) {
      float bb2 = ba2[0];
#pragma unroll
      for (int reg = 0; reg < 4; ++reg) {
        int row = i0 + w * 16 + q * 4 + reg;
        tw[row] = 1.f / (1.f + expf(-(part[reg] + bb2)));
      }
    }
  }
}

// ---------------------------------------------------------------------------
// Kernel 4: layer2 GEMM + row-norm fused: p = h @ w2.T + b2, fn = p/|p| -> bf16.
// Grid (64): block = 64 rows x all 256 cols. A-fragments read direct from
// global (hh is L2-resident); w2 col-tiles staged in LDS. acc = 16 f32x4.
// ---------------------------------------------------------------------------
__global__ __launch_bounds__(256) void gemm2norm_kernel(
    const u16* __restrict__ hh, const u16* __restrict__ w2b,
    const float* __restrict__ b2, u16* __restrict__ fnb) {
  int i0 = blockIdx.x * 64;
  int t = threadIdx.x;
  int lane = t & 63, w = t >> 6, m = lane & 15, q = lane >> 4;

  __shared__ __align__(16) u16 Bs[64 * 264];

  // A fragments: rows w*16+m, k = ks*32 + q*8 (8 x 16B, L2-hit)
  bf16x8 af[8];
#pragma unroll
  for (int ks = 0; ks < 8; ++ks)
    af[ks] = *(const bf16x8*)&hh[(i0 + w * 16 + m) * 256 + ks * 32 + q * 8];

  f32x4 acc[4][4];
#pragma unroll
  for (int n = 0; n < 4; ++n)
#pragma unroll
    for (int nt = 0; nt < 4; ++nt) acc[n][nt] = {0.f, 0.f, 0.f, 0.f};

  for (int n = 0; n < 4; ++n) {
    __syncthreads();
#pragma unroll
    for (int i = 0; i < 8; ++i) {
      int e = i * 256 + t;
      int row = e >> 5, kg = e & 31;
      *(uint4*)&Bs[row * 264 + kg * 8] = *(const uint4*)&w2b[(n * 64 + row) * 256 + kg * 8];
    }
    __syncthreads();
#pragma unroll
    for (int ks = 0; ks < 8; ++ks) {
      int koff = ks * 32 + q * 8;
#pragma unroll
      for (int nt = 0; nt < 4; ++nt) {
        bf16x8 bh = *(const bf16x8*)&Bs[(nt * 16 + m) * 264 + koff];
        acc[n][nt] = __builtin_amdgcn_mfma_f32_16x16x32_bf16(af[ks], bh, acc[n][nt], 0, 0, 0);
      }
    }
  }

  // bias + row sum-of-squares (each lane: 4 rows x 16 cols)
  float ss[4] = {0.f, 0.f, 0.f, 0.f};
#pragma unroll
  for (int n = 0; n < 4; ++n)
#pragma unroll
    for (int nt = 0; nt < 4; ++nt) {
      float bb = b2[n * 64 + nt * 16 + m];
#pragma unroll
      for (int reg = 0; reg < 4; ++reg) {
        float p = acc[n][nt][reg] + bb;
        acc[n][nt][reg] = p;
        ss[reg] += p * p;
      }
    }
  // reduce across the 16 m-lanes (covers all 256 cols)
  for (int off = 8; off > 0; off >>= 1) {
#pragma unroll
    for (int reg = 0; reg < 4; ++reg) ss[reg] += __shfl_xor(ss[reg], off, 64);
  }
  float inv[4];
#pragma unroll
  for (int reg = 0; reg < 4; ++reg)
    inv[reg] = 1.f / fmaxf(sqrtf(ss[reg]), 1e-12f);

#pragma unroll
  for (int n = 0; n < 4; ++n)
#pragma unroll
    for (int nt = 0; nt < 4; ++nt) {
      int col = n * 64 + nt * 16 + m;
#pragma unroll
      for (int reg = 0; reg < 4; ++reg) {
        int row = i0 + w * 16 + q * 4 + reg;
        fnb[row * 256 + col] = to_bf16(acc[n][nt][reg] * inv[reg]);
      }
    }
}

// ---------------------------------------------------------------------------
// Kernel 5: MFMA sim = fn @ fn.T (bf16). Triangular tiles tj>=ti.
// ---------------------------------------------------------------------------
__global__ __launch_bounds__(256) void sim_kernel(
    const u16* __restrict__ fnb, const float* __restrict__ tw,
    const int* __restrict__ selv, const int* __restrict__ tsp,
    float* __restrict__ denom, float* __restrict__ Prow, float* __restrict__ Ssum) {
  int b = blockIdx.y;
  int t = threadIdx.x;
  int lane = t & 63, w = t >> 6;
  int m = lane & 15, q = lane >> 4;

  int rem = blockIdx.x, ti = 0;
  while (rem >= (16 - ti)) { rem -= (16 - ti); ++ti; }
  int tj = ti + rem;
  bool diag = (ti == tj);
  int i0 = ti * 64, j0 = tj * 64;
  int base = b << 10;

  __shared__ __align__(16) u16 Ah[64 * 72];
  __shared__ __align__(16) u16 Bhh[64 * 72];
  __shared__ float drl[64], Prl[64];
  __shared__ float dclw[4][64], Pclw[4][64];
  __shared__ float swv[4];

  const u16* Bh = diag ? Ah : Bhh;

  f32x4 acc[4];
#pragma unroll
  for (int nt = 0; nt < 4; ++nt) acc[nt] = {0.f, 0.f, 0.f, 0.f};

  for (int kk = 0; kk < 4; ++kk) {
    __syncthreads();
#pragma unroll
    for (int p = 0; p < 2; ++p) {
      int e = p * 256 + t;
      int row = e >> 3, kg = e & 7;
      int lo = row * 72 + kg * 8;
      *(uint4*)&Ah[lo] = *(const uint4*)&fnb[(base + i0 + row) * 256 + kk * 64 + kg * 8];
      if (!diag)
        *(uint4*)&Bhh[lo] = *(const uint4*)&fnb[(base + j0 + row) * 256 + kk * 64 + kg * 8];
    }
    __syncthreads();
#pragma unroll
    for (int ks = 0; ks < 2; ++ks) {
      int koff = ks * 32 + q * 8;
      bf16x8 ah = *(const bf16x8*)&Ah[(w * 16 + m) * 72 + koff];
#pragma unroll
      for (int nt = 0; nt < 4; ++nt) {
        bf16x8 bh = *(const bf16x8*)&Bh[(nt * 16 + m) * 72 + koff];
        acc[nt] = __builtin_amdgcn_mfma_f32_16x16x32_bf16(ah, bh, acc[nt], 0, 0, 0);
      }
    }
  }

  int   gi[4], gj[4], si[4], sj[4], ci[4], cj[4];
  float twi[4], twj[4];
#pragma unroll
  for (int reg = 0; reg < 4; ++reg) {
    int i = i0 + w * 16 + q * 4 + reg;
    gi[reg] = i; twi[reg] = tw[base + i];
    si[reg] = selv[base + i]; ci[reg] = tsp[base + i];
  }
#pragma unroll
  for (int nt = 0; nt < 4; ++nt) {
    int j = j0 + nt * 16 + m;
    gj[nt] = j; twj[nt] = tw[base + j];
    sj[nt] = selv[base + j]; cj[nt] = tsp[base + j];
  }

  float dR[4] = {0, 0, 0, 0}, PR[4] = {0, 0, 0, 0};
  float dC[4] = {0, 0, 0, 0}, PC[4] = {0, 0, 0, 0};
  float Sp = 0.f;
#pragma unroll
  for (int nt = 0; nt < 4; ++nt) {
#pragma unroll
    for (int reg = 0; reg < 4; ++reg) {
      float s = acc[nt][reg];
      float e10 = __expf(s * INV_T);
      if (sj[nt]) dR[reg] += e10;
      if (si[reg]) dC[nt] += e10;
      if (si[reg] && sj[nt] && (ci[reg] == cj[nt]) && (s > THR) && (gi[reg] != gj[nt])) {
        float pw = twi[reg] * twj[nt];
        PR[reg] += pw;
        PC[nt] += pw;
        Sp += pw * s;
      }
    }
  }

  for (int off = 8; off > 0; off >>= 1) {
#pragma unroll
    for (int reg = 0; reg < 4; ++reg) {
      dR[reg] += __shfl_xor(dR[reg], off, 64);
      PR[reg] += __shfl_xor(PR[reg], off, 64);
    }
  }
  if (m == 0) {
#pragma unroll
    for (int reg = 0; reg < 4; ++reg) {
      drl[w * 16 + q * 4 + reg] = dR[reg];
      Prl[w * 16 + q * 4 + reg] = PR[reg];
    }
  }
  if (!diag) {
    for (int off = 32; off >= 16; off >>= 1) {
#pragma unroll
      for (int nt = 0; nt < 4; ++nt) {
        dC[nt] += __shfl_xor(dC[nt], off, 64);
        PC[nt] += __shfl_xor(PC[nt], off, 64);
      }
    }
    if (q == 0) {
#pragma unroll
      for (int nt = 0; nt < 4; ++nt) {
        dclw[w][nt * 16 + m] = dC[nt];
        Pclw[w][nt * 16 + m] = PC[nt];
      }
    }
  }
  for (int off = 32; off > 0; off >>= 1) Sp += __shfl_xor(Sp, off, 64);
  if (lane == 0) swv[w] = Sp;
  __syncthreads();

  if (t < 64) {
    atomicAdd(&denom[base + i0 + t], drl[t]);
    atomicAdd(&Prow [base + i0 + t], Prl[t]);
    if (!diag) {
      float dc = dclw[0][t] + dclw[1][t] + dclw[2][t] + dclw[3][t];
      float pc = Pclw[0][t] + Pclw[1][t] + Pclw[2][t] + Pclw[3][t];
      atomicAdd(&denom[base + j0 + t], dc);
      atomicAdd(&Prow [base + j0 + t], pc);
    }
  }
  if (t == 0) {
    float St = swv[0] + swv[1] + swv[2] + swv[3];
    atomicAdd(&Ssum[b], diag ? St : 2.f * St);
  }
}

// ---------------------------------------------------------------------------
// Kernel 6: finalize. loss_b = -(T/BT) * (S_b/T - sum_i P_i log D_i) / psum_b
// ---------------------------------------------------------------------------
__global__ __launch_bounds__(1024) void finalize_kernel(
    const float* __restrict__ denom, const float* __restrict__ Prow,
    const float* __restrict__ Ssum, float* __restrict__ out) {
  int t = threadIdx.x;
  int b = t >> 8, u = t & 255;
  float P = 0.f, L = 0.f;
#pragma unroll
  for (int q = 0; q < 4; ++q) {
    int s = u + q * 256;
    float p = Prow[b * SSEL + s];
    float D = denom[b * SSEL + s];
    P += p;
    L += p * logf(D > 0.f ? D : 1.f);
  }
  for (int off = 32; off > 0; off >>= 1) {
    P += __shfl_xor(P, off, 64);
    L += __shfl_xor(L, off, 64);
  }
  __shared__ float wP[16], wL[16];
  int lane = t & 63, w = t >> 6;
  if (lane == 0) { wP[w] = P; wL[w] = L; }
  __syncthreads();
  if (t == 0) {
    float total = 0.f, n = 0.f;
    for (int bb = 0; bb < BATCH; ++bb) {
      float psum = wP[4 * bb] + wP[4 * bb + 1] + wP[4 * bb + 2] + wP[4 * bb + 3];
      float lsum = wL[4 * bb] + wL[4 * bb + 1] + wL[4 * bb + 2] + wL[4 * bb + 3];
      if (psum > 0.f) {
        float wls = Ssum[bb] * INV_T - lsum;
        total += -RATIO * wls / psum;
        n += 1.f;
      }
    }
    out[0] = (n > 0.f) ? (total / n) : 0.f;
  }
}

// ---------------------------------------------------------------------------
extern "C" void kernel_launch(void* const* d_in, const int* in_sizes, int n_in,
                              void* d_out, int out_size, void* d_ws, size_t ws_size,
                              hipStream_t stream) {
  const float* feats = (const float*)d_in[0];
  const int*   labels = (const int*)d_in[1];
  const int*   sp     = (const int*)d_in[2];
  const float* w1  = (const float*)d_in[3];
  const float* b1  = (const float*)d_in[4];
  const float* w2  = (const float*)d_in[5];
  const float* b2  = (const float*)d_in[6];
  const float* wa1 = (const float*)d_in[7];
  const float* ba1 = (const float*)d_in[8];
  const float* wa2 = (const float*)d_in[9];
  const float* ba2 = (const float*)d_in[10];
  float* out = (float*)d_out;

  char* W = (char*)d_ws;
  u16* w1b = (u16*)W;               W += 65536 * 2;
  u16* w2b = (u16*)W;               W += 65536 * 2;
  u16* wab = (u16*)W;               W += 16384 * 2;
  u16* xh  = (u16*)W;               W += 1048576 * 2;
  u16* hh  = (u16*)W;               W += 1048576 * 2;
  u16* fnb = (u16*)W;               W += 1048576 * 2;
  float* tw   = (float*)W;          W += 4096 * 4;
  float* denom= (float*)W;          W += 4096 * 4;
  float* Prow = (float*)W;          W += 4096 * 4;
  float* Ssum = (float*)W;          W += 4 * 4;
  int*   idx  = (int*)W;            W += 4096 * 4;
  int*   selv = (int*)W;            W += 4096 * 4;
  int*   tsp  = (int*)W;            W += 4096 * 4;
  int*   counts = (int*)W;          W += 128 * 4;

  pack_weights<<<256, 256, 0, stream>>>(w1, w2, wa1, labels, w1b, w2b, wab,
                                        denom, Prow, Ssum, counts);
  select_scatter<<<BATCH * NCHUNK, 1024, 0, stream>>>(labels, sp, counts,
                                                      idx, selv, tsp);
  gather_cast<<<256, 256, 0, stream>>>(feats, idx, xh);
  gemm1_kernel<<<dim3(5, 64), 256, 0, stream>>>(xh, w1b, wab, b1, ba1,
                                                wa2, ba2, hh, tw);
  gemm2norm_kernel<<<64, 256, 0, stream>>>(hh, w2b, b2, fnb);
  sim_kernel<<<dim3(136, BATCH), 256, 0, stream>>>(fnb, tw, selv, tsp,
                                                   denom, Prow, Ssum);
  finalize_kernel<<<1, 1024, 0, stream>>>(denom, Prow, Ssum, out);
}